// Round 8
// baseline (69.122 us; speedup 1.0000x reference)
//
#include <hip/hip_runtime.h>

typedef float f32x4 __attribute__((ext_vector_type(4)));
typedef short s16x8 __attribute__((ext_vector_type(8)));
typedef unsigned short u16;
typedef unsigned int u32;

// Problem constants
// B=4, T=320, U=80, D=512, INNER=512, VOCAB=6, MAX_RLE=50
// X rows: 1280 enc rows (b*320+t), then 320 dec rows (b*80+u). 1600 total.
// out: base [102400*6] then rle [102400*50], fp32.

__device__ __forceinline__ u16 f2bf(float f) {
  u32 u = __float_as_uint(f);
  u32 r = (u + 0x7FFFu + ((u >> 16) & 1u)) >> 16;  // RNE
  return (u16)r;
}

// Packed f32x2 -> bf16x2 via explicit ISA op (R6-proven bit-identical to f2bf).
__device__ __forceinline__ u32 cvt_pk_bf16(float lo, float hi) {
  u32 r;
  asm("v_cvt_pk_bf16_f32 %0, %1, %2" : "=v"(r) : "v"(lo), "v"(hi));
  return r;
}

// tanh(x) = 1 - 2/(e^{2x}+1). Saturates correctly at +-inf via rcp(inf)=0.
// 5 VALU ops (2 trans), no clamp, no IEEE div sequence.
__device__ __forceinline__ float fast_tanh(float x) {
  float e = __expf(2.f * x);
  return __builtin_fmaf(-2.f, __builtin_amdgcn_rcpf(e + 1.f), 1.f);
}

// ---- fused prep: [0,400) cast X; [400,2448) pack W_f; [2448,2576) pack W_out + bias ----
__global__ void prep_all(const float* __restrict__ enc, const float* __restrict__ dec,
                         s16x8* __restrict__ Xb,
                         const float* __restrict__ Wf, u16* __restrict__ WfF,
                         const float* __restrict__ Wb, const float* __restrict__ bb,
                         const float* __restrict__ Wr, const float* __restrict__ br,
                         u16* __restrict__ WoF, float* __restrict__ bias_cat) {
  int bx = blockIdx.x;
  int tid = threadIdx.x;
  if (bx < 400) {
    int idx = bx * 256 + tid;  // 0..102399
    long e = (long)idx * 8;
    const float* src = (e < 655360) ? (enc + e) : (dec + (e - 655360));
    f32x4 a = *(const f32x4*)src;
    f32x4 b = *(const f32x4*)(src + 4);
    s16x8 o;
    o[0] = (short)f2bf(a[0]); o[1] = (short)f2bf(a[1]);
    o[2] = (short)f2bf(a[2]); o[3] = (short)f2bf(a[3]);
    o[4] = (short)f2bf(b[0]); o[5] = (short)f2bf(b[1]);
    o[6] = (short)f2bf(b[2]); o[7] = (short)f2bf(b[3]);
    Xb[idx] = o;
  } else if (bx < 2448) {
    int idx = (bx - 400) * 256 + tid;  // 0..524287
    int j = idx & 7;
    int lane = (idx >> 3) & 63;
    int kk = (idx >> 9) & 15;
    int nt = (idx >> 13) & 31;
    int part = idx >> 18;
    int n = nt * 16 + (lane & 15);
    int k = part * 512 + kk * 32 + ((lane >> 4) << 3) + j;
    WfF[idx] = f2bf(Wf[n * 1024 + k]);
  } else {
    int idx = (bx - 2448) * 256 + tid;  // 0..32767
    int j = idx & 7;
    int lane = (idx >> 3) & 63;
    int ks = (idx >> 9) & 15;
    int nt = idx >> 13;
    int v = nt * 16 + (lane & 15);
    int k = ks * 32 + ((lane >> 4) << 3) + j;
    float val = (v < 6) ? Wb[v * 512 + k] : (v < 56 ? Wr[(v - 6) * 512 + k] : 0.f);
    WoF[idx] = f2bf(val);
    if (bx == 2448 && tid < 64) {
      int vv = tid;
      bias_cat[vv] = (vv < 6) ? bb[vv] : (vv < 56 ? br[vv - 6] : 0.f);
    }
  }
}

// ---- E-GEMM: Ebf[1280][512] = enc*Wf[:, :512]^T + b_f ; Dc[320][512] = dec*Wf[:,512:]^T
__global__ __launch_bounds__(256) void egemm(const s16x8* __restrict__ Xb,
                                             const s16x8* __restrict__ WfF,
                                             const float* __restrict__ b_f,
                                             float* __restrict__ Ebf,
                                             float* __restrict__ Dc) {
  int ms = blockIdx.x >> 3;   // 0..24
  int ns = blockIdx.x & 7;    // 0..7
  int w = threadIdx.x >> 6, l = threadIdx.x & 63;
  int r0 = ms * 64 + w * 16;
  int part = (r0 >= 1280) ? 1 : 0;
  int n0 = ns * 64;
  int lrow = r0 + (l & 15);
  int khi = (l >> 4) << 3;  // 0,8,16,24
  f32x4 acc[4] = {};
#pragma unroll
  for (int kk = 0; kk < 16; ++kk) {
    s16x8 a = Xb[lrow * 64 + kk * 4 + (khi >> 3)];
#pragma unroll
    for (int nt = 0; nt < 4; ++nt) {
      int ntg = ns * 4 + nt;
      s16x8 bf = WfF[((part * 32 + ntg) * 16 + kk) * 64 + l];
      acc[nt] = __builtin_amdgcn_mfma_f32_16x16x32_bf16(a, bf, acc[nt], 0, 0, 0);
    }
  }
#pragma unroll
  for (int nt = 0; nt < 4; ++nt) {
    int n = n0 + nt * 16 + (l & 15);
    float bias = part ? 0.f : b_f[n];
#pragma unroll
    for (int q = 0; q < 4; ++q) {
      int row = r0 + ((l >> 4) << 2) + q;
      float val = acc[nt][q] + bias;
      if (part) Dc[(row - 1280) * 512 + n] = val;
      else      Ebf[row * 512 + n] = val;
    }
  }
}

// ---- main, barrier-free: grid 1280 = (b,t); block 320 = 5 waves x 16 u-rows.
// Each lane computes the h elements of its OWN A-fragment (row=l&15,
// k=(l>>4)*8+j -- the same per-lane map egemm uses), feeds MFMA directly
// from registers. No LDS, no barriers. B-fragments stream from WoF via L1.
__global__ __launch_bounds__(320, 2) void joint_main(const float* __restrict__ Ebf,
                                                     const float* __restrict__ Dc,
                                                     const s16x8* __restrict__ WoF,
                                                     const float* __restrict__ bias_cat,
                                                     float* __restrict__ out) {
  int bt = blockIdx.x;          // 0..1279 ; b = bt/320
  int b = bt / 320;
  int tid = threadIdx.x;
  int w = tid >> 6;             // wave 0..4 -> u rows [16w, 16w+16)
  int l = tid & 63;
  int u_base = w * 16;
  int urow = u_base + (l & 15);           // row this lane computes (A-frag row)
  int khi = (l >> 4) << 3;                // 0,8,16,24 (A-frag k base within k32)

  const float* dbase = Dc + (long)(b * 80 + urow) * 512 + khi;
  const float* ebase = Ebf + (long)bt * 512 + khi;

  float bias[4];
#pragma unroll
  for (int nt = 0; nt < 4; ++nt) bias[nt] = bias_cat[nt * 16 + (l & 15)];

  f32x4 acc[4] = {};

#pragma unroll
  for (int c = 0; c < 4; ++c) {
    // build this chunk's 4 A-fragments in registers (k = c*128 + kk*32 + khi + j)
    s16x8 afr[4];
#pragma unroll
    for (int kk = 0; kk < 4; ++kk) {
      const float* dp = dbase + c * 128 + kk * 32;
      const float* ep = ebase + c * 128 + kk * 32;
      f32x4 d0 = *(const f32x4*)dp;
      f32x4 d1 = *(const f32x4*)(dp + 4);
      f32x4 e0 = *(const f32x4*)ep;
      f32x4 e1 = *(const f32x4*)(ep + 4);
      float t[8];
#pragma unroll
      for (int j = 0; j < 4; ++j) {
        t[j]     = fast_tanh(e0[j] + d0[j]);
        t[j + 4] = fast_tanh(e1[j] + d1[j]);
      }
      union { s16x8 vv; u32 ww[4]; } hb;
#pragma unroll
      for (int k = 0; k < 4; ++k)
        hb.ww[k] = cvt_pk_bf16(t[2 * k], t[2 * k + 1]);
      afr[kk] = hb.vv;
    }
    // MFMA: 4 k-steps x 4 n-tiles, acc[nt] accumulates across kk and c
#pragma unroll
    for (int kk = 0; kk < 4; ++kk) {
      int ks = c * 4 + kk;
#pragma unroll
      for (int nt = 0; nt < 4; ++nt) {
        s16x8 bfr = WoF[(nt * 16 + ks) * 64 + l];
        acc[nt] = __builtin_amdgcn_mfma_f32_16x16x32_bf16(afr[kk], bfr, acc[nt], 0, 0, 0);
      }
    }
  }

  // epilogue: C/D map row=(l>>4)*4+q (u within wave tile), col=l&15 (v within nt)
  long pbase = (long)bt * 80 + u_base;
#pragma unroll
  for (int nt = 0; nt < 4; ++nt) {
    int v = nt * 16 + (l & 15);
#pragma unroll
    for (int q = 0; q < 4; ++q) {
      int ur = ((l >> 4) << 2) + q;
      long p = pbase + ur;
      float val = acc[nt][q] + bias[nt];
      if (v < 6)       out[p * 6 + v] = val;
      else if (v < 56) out[614400 + p * 50 + (v - 6)] = val;
    }
  }
}

extern "C" void kernel_launch(void* const* d_in, const int* in_sizes, int n_in,
                              void* d_out, int out_size, void* d_ws, size_t ws_size,
                              hipStream_t stream) {
  (void)in_sizes; (void)n_in; (void)out_size; (void)ws_size;
  const float* enc = (const float*)d_in[0];
  const float* dec = (const float*)d_in[1];
  const float* Wf  = (const float*)d_in[2];
  const float* bf  = (const float*)d_in[3];
  const float* Wb  = (const float*)d_in[4];
  const float* bb  = (const float*)d_in[5];
  const float* Wr  = (const float*)d_in[6];
  const float* br  = (const float*)d_in[7];
  float* out = (float*)d_out;
  char* ws = (char*)d_ws;

  s16x8* Xb     = (s16x8*)(ws);               // 1,638,400 B
  u16*   WfF    = (u16*)(ws + 1638400);       // 1,048,576 B
  u16*   WoF    = (u16*)(ws + 2686976);       //    65,536 B
  float* biasC  = (float*)(ws + 2752512);     //       256 B
  float* Ebf    = (float*)(ws + 2752768);     // 2,621,440 B
  float* Dc     = (float*)(ws + 5374208);     //   655,360 B
  // total 6,029,568 B of d_ws used

  prep_all<<<2576, 256, 0, stream>>>(enc, dec, Xb, Wf, WfF, Wb, bb, Wr, br, WoF, biasC);
  egemm<<<200, 256, 0, stream>>>(Xb, (const s16x8*)WfF, bf, Ebf, Dc);
  joint_main<<<1280, 320, 0, stream>>>(Ebf, Dc, (const s16x8*)WoF, biasC, out);
}